// Round 12
// baseline (339.194 us; speedup 1.0000x reference)
//
#include <hip/hip_runtime.h>
#include <hip/hip_bf16.h>
#include <stdint.h>

#define NN 100000
#define NE 1600000
#define FIN 128
#define HID 64
#define COUT 16

// two-phase placement: coarse bucket = 256 dest nodes
#define BUKSH 8
#define BUKN 256
#define NBUK ((NN + BUKN - 1) >> BUKSH)   // 391
#define CAP 5120                          // slab capacity: mean 4096 + 16 sigma
#define PART_NB 200                       // phase-A blocks
#define EPB (NE / PART_NB)                // 8000 edges per phase-A block

typedef unsigned long long u64;
typedef short bf16x8 __attribute__((ext_vector_type(8)));
typedef float f32x4 __attribute__((ext_vector_type(4)));

struct Flags { int f32; int i64; };

__device__ __forceinline__ float b2f(__hip_bfloat16 v) { return __bfloat162float(v); }

__device__ __forceinline__ float ldf(const void* p, size_t i, int f32) {
    return f32 ? ((const float*)p)[i]
               : __bfloat162float(((const __hip_bfloat16*)p)[i]);
}
__device__ __forceinline__ int lde(const void* p, size_t i, int i64) {
    return i64 ? (int)((const long long*)p)[i] : ((const int*)p)[i];
}
__device__ __forceinline__ void ld4bf(const __hip_bfloat16* p, float& x0, float& x1,
                                      float& x2, float& x3) {
    union { uint2 u; __hip_bfloat16 h[4]; } v;
    v.u = *(const uint2*)p;
    x0 = b2f(v.h[0]); x1 = b2f(v.h[1]); x2 = b2f(v.h[2]); x3 = b2f(v.h[3]);
}

// ---- K0: detect input dtypes on-device (one wave + ballot) ----
__global__ void k_detect(const unsigned short* xs, const int* ei32, Flags* fl) {
    int lane = threadIdx.x & 63;
    int huge = 0;
    for (int i = lane * 2; i < 1024; i += 128) {
        int e = (xs[i] >> 7) & 0xFF;
        if (e >= 0xC0) huge = 1;   // fp32 low-halves have random exponents; bf16 N(0,1) never
    }
    int odd_nonzero = 0;
    for (int i = 1 + lane * 2; i < 512; i += 128) {
        if (ei32[i] != 0) odd_nonzero = 1;                // int64 high words are all 0
    }
    u64 h = __ballot(huge), o = __ballot(odd_nonzero);
    if (lane == 0) { fl->f32 = (h != 0); fl->i64 = (o == 0); }
}

// ---- K1: argmin over edges with row==0 (atomics only on the rare hit) ----
__global__ void k_mink(const void* __restrict__ ei, const void* __restrict__ ew,
                       const Flags* __restrict__ fl, u64* __restrict__ minkey) {
    int e = blockIdx.x * blockDim.x + threadIdx.x;
    if (e >= NE) return;
    int r = lde(ei, e, fl->i64);
    if (r == 0) {
        float w = ldf(ew, e, fl->f32);
        u64 key = ((u64)__float_as_uint(w) << 32) | (unsigned)e;  // w>=0: bits monotone
        atomicMin(minkey, key);
    }
}

// ---- K2: phase-A — partition edges into 391 coarse buckets (LDS histogram) ----
// tmp record: low32 = src(17b) | nodeLow(8b)<<17 | delflag<<25 ; high32 = w bits
__global__ __launch_bounds__(256) void k_partA(const void* __restrict__ ei,
                                               const void* __restrict__ ew,
                                               const Flags* __restrict__ fl,
                                               const u64* __restrict__ minkey,
                                               int* __restrict__ cursorA,
                                               long long* __restrict__ tmp) {
    __shared__ int cnt[NBUK];
    __shared__ int base[NBUK];
    int b = blockIdx.x, t = threadIdx.x;
    int f32 = fl->f32, i64 = fl->i64;
    for (int i = t; i < NBUK; i += 256) cnt[i] = 0;
    __syncthreads();
    int e0 = b * EPB;
    for (int i = t; i < EPB; i += 256) {
        int c = lde(ei, (size_t)NE + e0 + i, i64);
        atomicAdd(&cnt[c >> BUKSH], 1);
    }
    __syncthreads();
    for (int i = t; i < NBUK; i += 256) {
        int n = cnt[i];
        base[i] = n ? atomicAdd(&cursorA[i], n) : 0;   // 78K global atomics total
    }
    __syncthreads();
    for (int i = t; i < NBUK; i += 256) cnt[i] = 0;
    __syncthreads();
    u64 k = *minkey;
    int eidx = (k == ~0ull) ? 0 : (int)(k & 0xffffffffu);  // argmin(all-inf)==0, like jnp
    for (int i = t; i < EPB; i += 256) {
        int e = e0 + i;
        int r = lde(ei, e, i64);
        int c = lde(ei, (size_t)NE + e, i64);
        float w = ldf(ew, e, f32);
        int buk = c >> BUKSH;
        int slot = base[buk] + atomicAdd(&cnt[buk], 1);
        if (slot < CAP) {   // never triggers (16-sigma slack); guard vs OOB only
            unsigned lo = (unsigned)r | (((unsigned)c & 255u) << 17)
                        | ((e == eidx) ? (1u << 25) : 0u);
            tmp[(size_t)buk * CAP + slot] = ((long long)__float_as_int(w) << 32) | lo;
        }
    }
}

// ---- K3: scan 391 bucket totals -> bucket bases in epack; rowptrN[NN]=NE ----
__global__ __launch_bounds__(512) void k_scanBk(const int* __restrict__ cursorA,
                                                int* __restrict__ bucketBase,
                                                int* __restrict__ rowptrN) {
    __shared__ int sm[512];
    int t = threadIdx.x;
    int v = 0;
    if (t < NBUK) { v = cursorA[t]; if (v > CAP) v = CAP; }
    sm[t] = v;
    for (int off = 1; off < 512; off <<= 1) {
        __syncthreads();
        int add = (t >= off) ? sm[t - off] : 0;
        __syncthreads();
        sm[t] += add;
    }
    __syncthreads();
    if (t < NBUK) bucketBase[t] = sm[t] - v;
    if (t == 511) rowptrN[NN] = sm[511];   // == NE
}

// ---- K4: phase-B — per-bucket CSR build in LDS + fused dinv1/dinv2 ----
__global__ __launch_bounds__(256) void k_partB(const int* __restrict__ cursorA,
                                               const int* __restrict__ bucketBase,
                                               const long long* __restrict__ tmp,
                                               int2* __restrict__ epack,
                                               int* __restrict__ rowptrN,
                                               float* __restrict__ dinv1,
                                               float* __restrict__ dinv2,
                                               int* __restrict__ delpos,
                                               const void* __restrict__ ei,
                                               const void* __restrict__ ew,
                                               const Flags* __restrict__ fl,
                                               const u64* __restrict__ minkey) {
    __shared__ int cnt[256];
    __shared__ int pfx[256];
    __shared__ u64 wsum[256];
    int b = blockIdx.x, t = threadIdx.x;
    cnt[t] = 0; wsum[t] = 0;
    __syncthreads();
    int count = cursorA[b]; if (count > CAP) count = CAP;
    const long long* ts = tmp + (size_t)b * CAP;
    for (int i = t; i < count; i += 256) {
        long long pk = ts[i];
        unsigned lo = (unsigned)pk;
        int nl = (int)((lo >> 17) & 255u);
        atomicAdd(&cnt[nl], 1);
        float w = __int_as_float((int)(pk >> 32));
        // w in [0,1]: w*2^32 exact in double — deg stays deterministic/exact
        atomicAdd(&wsum[nl], (u64)((double)w * 4294967296.0));
    }
    __syncthreads();
    int v = cnt[t];
    pfx[t] = v;
    for (int off = 1; off < 256; off <<= 1) {
        __syncthreads();
        int add = (t >= off) ? pfx[t - off] : 0;
        __syncthreads();
        pfx[t] += add;
    }
    __syncthreads();
    int excl = pfx[t] - v;
    int gbase = bucketBase[b];
    int node = (b << BUKSH) + t;
    if (node < NN) {
        rowptrN[node] = gbase + excl;
        float deg = (float)((double)wsum[t] * (1.0 / 4294967296.0));
        u64 k = *minkey;
        int eidx = (k == ~0ull) ? 0 : (int)(k & 0xffffffffu);
        int cmin = lde(ei, (size_t)NE + eidx, fl->i64);
        float wmin = ldf(ew, eidx, fl->f32);
        float d1 = deg + 1.0f;                 // +1 for self loop
        float d2 = d1 - ((node == cmin) ? wmin : 0.0f);
        dinv1[node] = rsqrtf(d1);
        dinv2[node] = rsqrtf(d2);
    }
    __syncthreads();
    cnt[t] = gbase + excl;       // reuse as global write cursor
    __syncthreads();
    for (int i = t; i < count; i += 256) {
        long long pk = ts[i];
        unsigned lo = (unsigned)pk;
        int nl = (int)((lo >> 17) & 255u);
        int pos = atomicAdd(&cnt[nl], 1);
        long long outpk = (pk & 0xFFFFFFFF00000000LL) | (lo & 0x1FFFFu);  // .x=src .y=w
        *(long long*)(epack + pos) = outpk;
        if (lo & (1u << 25)) *delpos = pos;
    }
}

// ---- K5a: fp32 path — LDS-tiled GEMM, 64 nodes x 64 cols per block ----
__global__ __launch_bounds__(256) void k_gemm1_f32(const float* __restrict__ x,
                                                   const float* __restrict__ W1,
                                                   const Flags* __restrict__ fl,
                                                   __hip_bfloat16* __restrict__ h1) {
    if (!fl->f32) return;
    __shared__ float smem[16384];        // ONE array, manually partitioned (r7 lesson)
    float* Wp = smem;
    float* Xs = smem + 8192;
    int t = threadIdx.x;
    int node0 = blockIdx.x * 64;
    {
        const float4* src = (const float4*)W1;
        float4* dst = (float4*)Wp;
        for (int i = t; i < 2048; i += 256) dst[i] = src[i];
    }
    {
        int xlim = (NN - node0) * (FIN / 4);
        if (xlim > 2048) xlim = 2048;
        const float4* src = (const float4*)(x + (size_t)node0 * FIN);
        float4* dst = (float4*)Xs;
        for (int i = t; i < xlim; i += 256) dst[i] = src[i];
    }
    __syncthreads();
    int col4 = (t & 15) * 4;
    int nb = t >> 4;
    float4 a0 = {0,0,0,0}, a1 = a0, a2 = a0, a3 = a0;
#pragma unroll 8
    for (int k = 0; k < FIN; k += 4) {
        float4 w0 = *(const float4*)&Wp[(k + 0) * HID + col4];
        float4 w1 = *(const float4*)&Wp[(k + 1) * HID + col4];
        float4 w2 = *(const float4*)&Wp[(k + 2) * HID + col4];
        float4 w3 = *(const float4*)&Wp[(k + 3) * HID + col4];
        float4 xv;
#define GEMM1_STEP(ACC, NOFF)                                            \
        xv = *(const float4*)&Xs[(nb + NOFF) * FIN + k];                 \
        ACC.x += xv.x * w0.x + xv.y * w1.x + xv.z * w2.x + xv.w * w3.x;  \
        ACC.y += xv.x * w0.y + xv.y * w1.y + xv.z * w2.y + xv.w * w3.y;  \
        ACC.z += xv.x * w0.z + xv.y * w1.z + xv.z * w2.z + xv.w * w3.z;  \
        ACC.w += xv.x * w0.w + xv.y * w1.w + xv.z * w2.w + xv.w * w3.w;
        GEMM1_STEP(a0, 0)
        GEMM1_STEP(a1, 16)
        GEMM1_STEP(a2, 32)
        GEMM1_STEP(a3, 48)
#undef GEMM1_STEP
    }
    float4 accs[4] = {a0, a1, a2, a3};
#pragma unroll
    for (int nn = 0; nn < 4; ++nn) {
        int node = node0 + nb + nn * 16;
        if (node < NN) {
            union { uint2 u; __hip_bfloat16 h[4]; } pk;
            pk.h[0] = __float2bfloat16(accs[nn].x);
            pk.h[1] = __float2bfloat16(accs[nn].y);
            pk.h[2] = __float2bfloat16(accs[nn].z);
            pk.h[3] = __float2bfloat16(accs[nn].w);
            *(uint2*)(h1 + (size_t)node * HID + col4) = pk.u;
        }
    }
}

// ---- K5b: bf16-input path (insurance; exits instantly when inputs are fp32) ----
__global__ __launch_bounds__(256) void k_gemm1_mfma(const __hip_bfloat16* __restrict__ x,
                                                    const unsigned short* __restrict__ W1,
                                                    const Flags* __restrict__ fl,
                                                    __hip_bfloat16* __restrict__ h1) {
    if (fl->f32) return;
    __shared__ unsigned short Wf[8192];
    int t = threadIdx.x;
    for (int i = t; i < 8192; i += 256) {
        int k = i >> 6;
        int n = i & 63;
        int kc = k >> 5, kr = k & 31;
        int q = kr >> 3, j = kr & 7;
        int n0 = n >> 4, col = n & 15;
        Wf[((((n0 << 2) | kc) << 2) | q) * 128 + col * 8 + j] = W1[i];
    }
    __syncthreads();
    int wave = t >> 6, lane = t & 63;
    int quad = lane >> 4, col = lane & 15;
    bf16x8 B[4][4];
#pragma unroll
    for (int n0 = 0; n0 < 4; ++n0)
#pragma unroll
        for (int kc = 0; kc < 4; ++kc)
            B[kc][n0] = *(const bf16x8*)&Wf[((((n0 << 2) | kc) << 2) | quad) * 128 + col * 8];
    int tile0 = (blockIdx.x * 4 + wave) * 4;
#pragma unroll 1
    for (int i = 0; i < 4; ++i) {
        int node0 = (tile0 + i) * 16;
        if (node0 >= NN) return;
        const __hip_bfloat16* xp = x + (size_t)(node0 + col) * FIN + quad * 8;
        f32x4 a0 = {0.f, 0.f, 0.f, 0.f}, a1 = a0, a2 = a0, a3 = a0;
#pragma unroll
        for (int kc = 0; kc < 4; ++kc) {
            bf16x8 A = *(const bf16x8*)(xp + kc * 32);
            a0 = __builtin_amdgcn_mfma_f32_16x16x32_bf16(A, B[kc][0], a0, 0, 0, 0);
            a1 = __builtin_amdgcn_mfma_f32_16x16x32_bf16(A, B[kc][1], a1, 0, 0, 0);
            a2 = __builtin_amdgcn_mfma_f32_16x16x32_bf16(A, B[kc][2], a2, 0, 0, 0);
            a3 = __builtin_amdgcn_mfma_f32_16x16x32_bf16(A, B[kc][3], a3, 0, 0, 0);
        }
        __hip_bfloat16* hp = h1 + (size_t)(node0 + quad * 4) * HID + col;
#pragma unroll
        for (int r = 0; r < 4; ++r) {
            hp[(size_t)r * HID + 0]  = __float2bfloat16(a0[r]);
            hp[(size_t)r * HID + 16] = __float2bfloat16(a1[r]);
            hp[(size_t)r * HID + 32] = __float2bfloat16(a2[r]);
            hp[(size_t)r * HID + 48] = __float2bfloat16(a3[r]);
        }
    }
}

// ---- K6: FUSED agg1 + epilogue1 + gemm2: h2 = relu(agg(h1)+...) @ W2 ----
// grid = NN/16 = 6250 exact blocks -> no early exits; __syncthreads is uniform.
__global__ __launch_bounds__(256) void k_agg1f(const int* __restrict__ rowptrN,
                                               const int2* __restrict__ epack,
                                               const float* __restrict__ dinv1,
                                               const __hip_bfloat16* __restrict__ h1,
                                               const void* __restrict__ b1,
                                               const void* __restrict__ W2,
                                               const Flags* __restrict__ fl,
                                               float* __restrict__ h2) {
    __shared__ float Ws[HID * COUT];        // 4 KB
    __shared__ float tile[16][16][16];      // [group][out_j][lane] 16 KB
    int t = threadIdx.x;
    int f32 = fl->f32;
    for (int i = t; i < HID * COUT; i += 256) Ws[i] = ldf(W2, i, f32);
    __syncthreads();
    int g = t >> 4;                 // group (node) within block
    int n = blockIdx.x * 16 + g;
    int l = t & 15;
    int f = l * 4;
    int wbase = t & 48;             // group base lane within wave
    float dn = dinv1[n];
    int p0 = rowptrN[n], p1 = rowptrN[n + 1];
    float a0 = 0.f, a1 = 0.f, a2 = 0.f, a3 = 0.f;
    for (int p = p0; p < p1; p += 16) {
        int idx = p + l;
        int2 ev = make_int2(0, 0);
        float cw = 0.f;
        if (idx < p1) {
            ev = epack[idx];
            cw = dinv1[ev.x] * __int_as_float(ev.y);
        }
        int cnt = p1 - p; if (cnt > 16) cnt = 16;
        for (int j = 0; j < cnt; ++j) {
            int   r = __shfl(ev.x, wbase + j);
            float c = __shfl(cw,   wbase + j);
            float x0, x1, x2, x3;
            ld4bf(h1 + (size_t)r * HID + f, x0, x1, x2, x3);
            a0 += c * x0; a1 += c * x1; a2 += c * x2; a3 += c * x3;
        }
    }
    float x0, x1, x2, x3;
    ld4bf(h1 + (size_t)n * HID + f, x0, x1, x2, x3);
    float s = dn * dn;
    float o0 = fmaxf(dn * a0 + s * x0 + ldf(b1, f + 0, f32), 0.f);
    float o1 = fmaxf(dn * a1 + s * x1 + ldf(b1, f + 1, f32), 0.f);
    float o2 = fmaxf(dn * a2 + s * x2 + ldf(b1, f + 2, f32), 0.f);
    float o3 = fmaxf(dn * a3 + s * x3 + ldf(b1, f + 3, f32), 0.f);
    // partials for the 16 layer-2 outputs over this lane's 4 k's
    float pt[16];
#pragma unroll
    for (int j = 0; j < 16; ++j) pt[j] = 0.f;
    {
        const float* w0 = &Ws[(f + 0) * COUT];
        const float* w1 = &Ws[(f + 1) * COUT];
        const float* w2 = &Ws[(f + 2) * COUT];
        const float* w3 = &Ws[(f + 3) * COUT];
#pragma unroll
        for (int j = 0; j < 16; ++j)
            pt[j] = o0 * w0[j] + o1 * w1[j] + o2 * w2[j] + o3 * w3[j];
    }
    __syncthreads();   // tile reuse boundary (uniform: grid exact, no early returns)
#pragma unroll
    for (int j = 0; j < 16; ++j) tile[g][j][l] = pt[j];
    __syncthreads();
    // lane l sums output j=l over the 16 lanes' partials (contiguous row)
    const float4* row = (const float4*)&tile[g][l][0];
    float4 s0 = row[0], s1 = row[1], s2 = row[2], s3 = row[3];
    float sum = (s0.x + s0.y + s0.z + s0.w) + (s1.x + s1.y + s1.z + s1.w)
              + (s2.x + s2.y + s2.z + s2.w) + (s3.x + s3.y + s3.z + s3.w);
    h2[(size_t)n * COUT + l] = sum;
}

// ---- K7: gather-aggregate layer 2, shfl-broadcast (4-lane groups) ----
__global__ __launch_bounds__(256) void k_agg2(const int* __restrict__ rowptrN,
                                              const int2* __restrict__ epack,
                                              const float* __restrict__ dinv2,
                                              const float* __restrict__ h2,
                                              const void* __restrict__ bias2,
                                              const Flags* __restrict__ fl,
                                              const int* __restrict__ delpos,
                                              void* __restrict__ out) {
    int t = threadIdx.x;
    int n = blockIdx.x * 64 + (t >> 2);
    if (n >= NN) return;
    int l = t & 3;
    int f = l * 4;
    int wbase = t & 60;
    int f32 = fl->f32;
    int dp = *delpos;
    float dn = dinv2[n];
    int p0 = rowptrN[n], p1 = rowptrN[n + 1];
    float a0 = 0.f, a1 = 0.f, a2 = 0.f, a3 = 0.f;
    for (int p = p0; p < p1; p += 4) {
        int idx = p + l;
        int rr = 0;
        float cw = 0.f;
        if (idx < p1) {
            int2 ev = epack[idx];
            float w = (idx == dp) ? 0.f : __int_as_float(ev.y);
            rr = ev.x;
            cw = dinv2[rr] * w;
        }
        int cnt = p1 - p; if (cnt > 4) cnt = 4;
        for (int j = 0; j < cnt; ++j) {
            int   r = __shfl(rr, wbase + j);
            float c = __shfl(cw, wbase + j);
            const float4 hv = *(const float4*)(h2 + (size_t)r * COUT + f);
            a0 += c * hv.x; a1 += c * hv.y; a2 += c * hv.z; a3 += c * hv.w;
        }
    }
    float s = dn * dn;
    const float4 hn = *(const float4*)(h2 + (size_t)n * COUT + f);
    float o0 = dn * a0 + s * hn.x + ldf(bias2, f + 0, f32);
    float o1 = dn * a1 + s * hn.y + ldf(bias2, f + 1, f32);
    float o2 = dn * a2 + s * hn.z + ldf(bias2, f + 2, f32);
    float o3 = dn * a3 + s * hn.w + ldf(bias2, f + 3, f32);
    size_t idx = (size_t)n * COUT + f;
    if (f32) {
        float* op = (float*)out + idx;
        op[0] = o0; op[1] = o1; op[2] = o2; op[3] = o3;
    } else {
        union { uint2 u; __hip_bfloat16 h[4]; } pk;
        pk.h[0] = __float2bfloat16(o0); pk.h[1] = __float2bfloat16(o1);
        pk.h[2] = __float2bfloat16(o2); pk.h[3] = __float2bfloat16(o3);
        *(uint2*)((__hip_bfloat16*)out + idx) = pk.u;
    }
}

extern "C" void kernel_launch(void* const* d_in, const int* in_sizes, int n_in,
                              void* d_out, int out_size, void* d_ws, size_t ws_size,
                              hipStream_t stream) {
    const void* x  = d_in[0];
    const void* ei = d_in[1];
    const void* ew = d_in[2];
    const void* W1 = d_in[3];
    const void* b1 = d_in[4];
    const void* W2 = d_in[5];
    const void* b2 = d_in[6];

    // workspace ~50 MB, no aliasing needed (out1 eliminated by fusion)
    char* wsb = (char*)d_ws;
    float* dinv1    = (float*)wsb;                     wsb += (size_t)NN * 4;
    float* dinv2    = (float*)wsb;                     wsb += (size_t)NN * 4;
    int*   rowptrN  = (int*)wsb;                       wsb += (size_t)(NN + 1) * 4;
    int*   cursorA  = (int*)wsb;                       wsb += (size_t)NBUK * 4;
    int*   bucketBase = (int*)wsb;                     wsb += (size_t)NBUK * 4;
    wsb = (char*)(((uintptr_t)wsb + 15) & ~(uintptr_t)15);
    int2*  epack    = (int2*)wsb;                      wsb += (size_t)NE * 8;
    __hip_bfloat16* h1 = (__hip_bfloat16*)wsb;         wsb += (size_t)NN * HID * 2;
    float* h2       = (float*)wsb;                     wsb += (size_t)NN * COUT * 4;
    long long* tmp  = (long long*)wsb;                 wsb += (size_t)NBUK * CAP * 8;
    u64*   minkey   = (u64*)wsb;                       wsb += 8;
    Flags* fl       = (Flags*)wsb;                     wsb += 8;
    int*   delpos   = (int*)wsb;                       wsb += 8;

    hipMemsetAsync(cursorA, 0, (size_t)NBUK * 4, stream);
    hipMemsetAsync(minkey, 0xFF, 8, stream);
    hipMemsetAsync(delpos, 0xFF, 4, stream);

    k_detect<<<1, 64, 0, stream>>>((const unsigned short*)x, (const int*)ei, fl);
    k_mink<<<(NE + 255) / 256, 256, 0, stream>>>(ei, ew, fl, minkey);
    k_partA<<<PART_NB, 256, 0, stream>>>(ei, ew, fl, minkey, cursorA, tmp);
    k_scanBk<<<1, 512, 0, stream>>>(cursorA, bucketBase, rowptrN);
    k_partB<<<NBUK, 256, 0, stream>>>(cursorA, bucketBase, tmp, epack, rowptrN,
                                      dinv1, dinv2, delpos, ei, ew, fl, minkey);
    k_gemm1_f32<<<(NN + 63) / 64, 256, 0, stream>>>((const float*)x, (const float*)W1,
                                                    fl, h1);
    k_gemm1_mfma<<<(NN / 16 + 15) / 16, 256, 0, stream>>>((const __hip_bfloat16*)x,
                                                          (const unsigned short*)W1, fl, h1);
    k_agg1f<<<NN / 16, 256, 0, stream>>>(rowptrN, epack, dinv1, h1, b1, W2, fl, h2);
    k_agg2<<<(NN + 63) / 64, 256, 0, stream>>>(rowptrN, epack, dinv2, h2, b2, fl,
                                               delpos, d_out);
}